// Round 11
// baseline (80.905 us; speedup 1.0000x reference)
//
#include <hip/hip_runtime.h>

#define NP 4
#define NH 8
#define HD 32
#define CD 256
#define NN 1728
#define NT_TILES 27
#define TILE_E 2048   // elements per (ph,tile): 64n x 32c
// SCALE * log2(e): Q pre-scaled so QK^T scores are exp2-ready
#define SCALE_Q2 (0.17677669529663687f * 1.4426950408889634f)

typedef __bf16 bf16x8 __attribute__((ext_vector_type(8)));
typedef __bf16 bf16x4_t __attribute__((ext_vector_type(4)));
typedef short short4_t __attribute__((ext_vector_type(4)));
typedef float f32x4 __attribute__((ext_vector_type(4)));
typedef unsigned short ushort4_t __attribute__((ext_vector_type(4)));
typedef unsigned short ushort8_t __attribute__((ext_vector_type(8)));

__device__ __forceinline__ float bf2f(unsigned short u) {
  unsigned int v = ((unsigned int)u) << 16;
  return __builtin_bit_cast(float, v);
}
__device__ __forceinline__ unsigned short f2bf(float f) {
  unsigned int v = __builtin_bit_cast(unsigned int, f);
  unsigned int r = (v + 0x7FFFu + ((v >> 16) & 1u)) >> 16;
  return (unsigned short)r;
}

// K0: blocks [0,864): x fp32 [p][C][N] -> xt bf16 [p][N][C] (LDS tile transpose)
//     blocks [864,1120): convert weights fp32 -> bf16
__global__ void k_prep(const float* __restrict__ x, unsigned short* __restrict__ xt,
                       const float* __restrict__ wqkv, const float* __restrict__ wproj,
                       unsigned short* __restrict__ wq_b, unsigned short* __restrict__ wp_b) {
  __shared__ __attribute__((aligned(16))) unsigned short tile[64 * 40]; // 80B rows
  int bid = blockIdx.x;
  int t = threadIdx.x;
  if (bid >= 864) {
    int idx = ((bid - 864) * 256 + t) * 4;
    const float* src;
    unsigned short* dst;
    if (idx < 196608) { src = wqkv + idx; dst = wq_b + idx; }
    else { src = wproj + (idx - 196608); dst = wp_b + (idx - 196608); }
    float4 v = *(const float4*)src;
    ushort4_t o;
    o[0] = f2bf(v.x); o[1] = f2bf(v.y); o[2] = f2bf(v.z); o[3] = f2bf(v.w);
    *(ushort4_t*)dst = o;
    return;
  }
  int nb = (bid % 27) * 64, cb = ((bid / 27) & 7) * 32, p = bid / 216;
  {
    int c = t >> 3, ch = t & 7;
    const float* src = x + ((size_t)p * CD + cb + c) * NN + nb + ch * 8;
    float4 v0 = *(const float4*)src;
    float4 v1 = *(const float4*)(src + 4);
    int base = ch * 8;
    tile[(base + 0) * 40 + c] = f2bf(v0.x);
    tile[(base + 1) * 40 + c] = f2bf(v0.y);
    tile[(base + 2) * 40 + c] = f2bf(v0.z);
    tile[(base + 3) * 40 + c] = f2bf(v0.w);
    tile[(base + 4) * 40 + c] = f2bf(v1.x);
    tile[(base + 5) * 40 + c] = f2bf(v1.y);
    tile[(base + 6) * 40 + c] = f2bf(v1.z);
    tile[(base + 7) * 40 + c] = f2bf(v1.w);
  }
  __syncthreads();
  {
    int n = t >> 2, ch = t & 3;
    *(ushort8_t*)(xt + ((size_t)p * NN + nb + n) * CD + cb + ch * 8) =
        *(const ushort8_t*)&tile[n * 40 + ch * 8];
  }
}

// K1: qkv = xt * wqkv^T. Each block is entirely Q (ot 0-3), K (4-7) or V (8-11).
// Q/K epilogue: LDS-bounce [64][72] -> 2 vectorized ushort8 stores per thread.
// Layouts: Qt [ph][n][32] (scaled); Kt [ph][tile][nf4][chunk64][8];
//          Vv [ph][tile][nfcb8][chunk64][4].
__global__ __launch_bounds__(256) void k_qkv(const unsigned short* __restrict__ xt,
                                             const unsigned short* __restrict__ wqkv,
                                             unsigned short* __restrict__ Qt,
                                             unsigned short* __restrict__ Kt,
                                             unsigned short* __restrict__ Vv) {
  __shared__ __attribute__((aligned(16))) unsigned short smem[64 * 72]; // 9216B
  int p = blockIdx.z, ot = blockIdx.y, nt = blockIdx.x;
  int tid = threadIdx.x, w = tid >> 6, lane = tid & 63, l15 = lane & 15, g = lane >> 4;
  int nbase = nt * 64 + w * 16;
  f32x4 acc[4] = {};
  const unsigned short* arow = xt + ((size_t)p * NN + nbase + l15) * CD + g * 8;
  const unsigned short* wrow = wqkv + ((size_t)(ot * 64 + l15)) * CD + g * 8;
  for (int ks = 0; ks < 8; ks++) {
    bf16x8 a = *(const bf16x8*)(arow + ks * 32);
#pragma unroll
    for (int ob = 0; ob < 4; ob++) {
      bf16x8 b = *(const bf16x8*)(wrow + ob * 16 * CD + ks * 32);
      acc[ob] = __builtin_amdgcn_mfma_f32_16x16x32_bf16(a, b, acc[ob], 0, 0, 0);
    }
  }
  int wq = ot >> 2;
  if (wq == 2) {
    // V: direct ushort4 stores (k-contiguous in tiled layout)
#pragma unroll
    for (int ob = 0; ob < 4; ob++) {
      int o = ot * 64 + ob * 16 + l15;
      int rem = o & 255, h = rem >> 5, cc = rem & 31;
      size_t tb = (size_t)(p * NH + h) * (NT_TILES * TILE_E) + nt * TILE_E;
      ushort4_t vs;
      for (int r = 0; r < 4; r++) vs[r] = f2bf(acc[ob][r]);
      *(ushort4_t*)(Vv + tb + (w * 2 + (cc >> 4)) * 256 + (g * 16 + (cc & 15)) * 4) = vs;
    }
    return;
  }
  // Q/K: bounce through LDS, then vectorized stores
  float sc = (wq == 0) ? SCALE_Q2 : 1.0f;
#pragma unroll
  for (int ob = 0; ob < 4; ob++)
    for (int r = 0; r < 4; r++)
      smem[(w * 16 + g * 4 + r) * 72 + ob * 16 + l15] = f2bf(acc[ob][r] * sc);
  __syncthreads();
#pragma unroll
  for (int i = 0; i < 2; i++) {
    int cid = i * 256 + tid;
    int row = cid >> 3, oc8 = cid & 7;
    ushort8_t vv = *(const ushort8_t*)&smem[row * 72 + oc8 * 8];
    int n = nt * 64 + row;
    if (wq == 0) {
      int h = ot * 2 + (oc8 >> 2), cc8 = (oc8 & 3) * 8;
      *(ushort8_t*)(Qt + ((size_t)(p * NH + h) * NN + n) * HD + cc8) = vv;
    } else {
      int h = (ot - 4) * 2 + (oc8 >> 2), cc8 = (oc8 & 3) * 8;
      size_t tb = (size_t)(p * NH + h) * (NT_TILES * TILE_E) + nt * TILE_E;
      *(ushort8_t*)(Kt + tb + (row >> 4) * 512 + ((cc8 >> 3) * 16 + (row & 15)) * 8) = vv;
    }
  }
}

// K2: flash attention, swapped-operand, shift-0 exact softmax, split-KV x2.
// K staged in LDS (shared by 4 waves), KVBLK=128 pairs; V read DIRECT from
// global (L2-hot, 512B-dense frags, read once per wave -> staging was pure
// overhead, m169 lesson). LDS 16KB/block.
__global__ __launch_bounds__(256) void k_attn(const unsigned short* __restrict__ Qt,
                                              const unsigned short* __restrict__ Kt,
                                              const unsigned short* __restrict__ Vv,
                                              unsigned short* __restrict__ op0,
                                              unsigned short* __restrict__ op1,
                                              float* __restrict__ Lp) {
  __shared__ __attribute__((aligned(16))) unsigned char lds[2 * 8192]; // 2 x K-pair
  int tid = threadIdx.x, w = tid >> 6, lane = tid & 63, l15 = lane & 15, g = lane >> 4;
  int mt = blockIdx.x, ph = blockIdx.y, z = blockIdx.z;
  int tA = z * 14;
  int nPair = z ? 6 : 7;
  bool tail = (z == 1);
  bf16x8 qfrag = *(const bf16x8*)(Qt + ((size_t)ph * NN + mt * 64 + w * 16 + l15) * HD + g * 8);
  const unsigned short* ktb = Kt + (size_t)ph * (NT_TILES * TILE_E);
  const unsigned short* vbg = Vv + (size_t)ph * (NT_TILES * TILE_E);
  f32x4 lsum = {0.f, 0.f, 0.f, 0.f};
  f32x4 oacc[2] = {};  // O^T: col=m=l15, rows c = cb*16 + g*4 + rr
  f32x4 zacc = {0.f, 0.f, 0.f, 0.f};
  const int so = tid * 16;
  // prologue: stage K pair 0 into buffer 0
  *(ushort8_t*)(lds + so)        = *(const ushort8_t*)(ktb + tA * TILE_E + tid * 8);
  *(ushort8_t*)(lds + 4096 + so) = *(const ushort8_t*)(ktb + (tA + 1) * TILE_E + tid * 8);
  __syncthreads();
  auto compute = [&](const unsigned char* kb, int nt) {
    // V frags: address-only dependence -> loads hoist above QK/exp (~400cy cover)
    const unsigned short* vt = vbg + nt * TILE_E;
    ushort4_t vq[8];
#pragma unroll
    for (int q = 0; q < 8; q++) vq[q] = *(const ushort4_t*)(vt + q * 256 + lane * 4);
    f32x4 s[4];
#pragma unroll
    for (int nf = 0; nf < 4; nf++) {
      bf16x8 kbv = *(const bf16x8*)(kb + nf * 1024 + lane * 16);
      s[nf] = __builtin_amdgcn_mfma_f32_16x16x32_bf16(kbv, qfrag, zacc, 0, 0, 0);
    }
    short4_t pa[4];
#pragma unroll
    for (int nf = 0; nf < 4; nf++) {
      f32x4 e;
#pragma unroll
      for (int r = 0; r < 4; r++) e[r] = __builtin_amdgcn_exp2f(s[nf][r]);
      lsum += e;
      bf16x4_t t;
#pragma unroll
      for (int r = 0; r < 4; r++) t[r] = (__bf16)e[r];
      pa[nf] = __builtin_bit_cast(short4_t, t);
    }
#pragma unroll
    for (int nf = 0; nf < 4; nf++) {
#pragma unroll
      for (int cb = 0; cb < 2; cb++) {
        short4_t va = __builtin_bit_cast(short4_t, vq[nf * 2 + cb]);
        oacc[cb] = __builtin_amdgcn_mfma_f32_16x16x16bf16_1k(va, pa[nf], oacc[cb], 0, 0, 0);
      }
    }
  };
  for (int pr = 0; pr < nPair; pr++) {
    unsigned char* buf = lds + (pr & 1) * 8192;
    unsigned char* bufN = lds + ((pr + 1) & 1) * 8192;
    ushort8_t kr0, kr1;
    bool pre = (pr + 1 < nPair);
    bool preT = tail && (pr + 1 == nPair);
    if (pre) {
      int d = tA + 2 * (pr + 1);
      kr0 = *(const ushort8_t*)(ktb + d * TILE_E + tid * 8);
      kr1 = *(const ushort8_t*)(ktb + (d + 1) * TILE_E + tid * 8);
    } else if (preT) {
      kr0 = *(const ushort8_t*)(ktb + 26 * TILE_E + tid * 8);
    }
    compute(buf, tA + 2 * pr);
    compute(buf + 4096, tA + 2 * pr + 1);
    if (pre) {
      *(ushort8_t*)(bufN + so) = kr0;
      *(ushort8_t*)(bufN + 4096 + so) = kr1;
    } else if (preT) {
      *(ushort8_t*)(bufN + so) = kr0;
    }
    __syncthreads();
  }
  if (tail) {
    unsigned char* buf = lds + (nPair & 1) * 8192;
    compute(buf, 26);
  }
  // deferred cross-lane sum reduce; store raw partials (no normalization yet)
  float total = lsum[0] + lsum[1] + lsum[2] + lsum[3];
  total += __shfl_xor(total, 16);
  total += __shfl_xor(total, 32);
  int m = mt * 64 + w * 16 + l15;
  unsigned short* op = z ? op1 : op0;
  if (g == 0) Lp[(size_t)z * 32 * NN + (size_t)ph * NN + m] = total;
#pragma unroll
  for (int cb = 0; cb < 2; cb++) {
    ushort4_t vs;
#pragma unroll
    for (int rr = 0; rr < 4; rr++) vs[rr] = f2bf(oacc[cb][rr]);
    *(ushort4_t*)(op + ((size_t)ph * NN + m) * 32 + cb * 16 + g * 4) = vs;
  }
}

// K3: fused combine+proj: out[p][o][n] = wproj · [(O0+O1)/(L0+L1)] + bias (fp32 out)
// 864 blocks x 128 thr (2 waves); block = 32o x 64n; wave = 32o x 32n.
__global__ __launch_bounds__(128) void k_proj(const unsigned short* __restrict__ op0,
                                              const unsigned short* __restrict__ op1,
                                              const float* __restrict__ Lp,
                                              const unsigned short* __restrict__ wproj,
                                              const float* __restrict__ bproj,
                                              float* __restrict__ out) {
  int p = blockIdx.z, oy = blockIdx.y, nt = blockIdx.x;
  int tid = threadIdx.x, w = tid >> 6, lane = tid & 63, l15 = lane & 15, g = lane >> 4;
  f32x4 acc[2][2] = {};  // [i n-subtile][ob]
  const unsigned short* wrow = wproj + ((size_t)(oy * 32 + l15)) * CD + g * 8;
  for (int ks = 0; ks < 8; ks++) {
    bf16x8 b0 = *(const bf16x8*)(wrow + ks * 32);
    bf16x8 b1 = *(const bf16x8*)(wrow + 16 * CD + ks * 32);
#pragma unroll
    for (int i = 0; i < 2; i++) {
      int n = nt * 64 + w * 32 + i * 16 + l15;
      size_t r = (size_t)(p * NH + ks) * NN + n;
      float inv = 1.0f / (Lp[r] + Lp[(size_t)32 * NN + r]);
      ushort8_t a0 = *(const ushort8_t*)(op0 + r * 32 + g * 8);
      ushort8_t a1 = *(const ushort8_t*)(op1 + r * 32 + g * 8);
      bf16x8 a;
#pragma unroll
      for (int j = 0; j < 8; j++) a[j] = (__bf16)((bf2f(a0[j]) + bf2f(a1[j])) * inv);
      acc[i][0] = __builtin_amdgcn_mfma_f32_16x16x32_bf16(a, b0, acc[i][0], 0, 0, 0);
      acc[i][1] = __builtin_amdgcn_mfma_f32_16x16x32_bf16(a, b1, acc[i][1], 0, 0, 0);
    }
  }
#pragma unroll
  for (int i = 0; i < 2; i++)
    for (int ob = 0; ob < 2; ob++) {
      int o = oy * 32 + ob * 16 + l15;
      float bias = bproj[o];
      int nrow = nt * 64 + w * 32 + i * 16 + g * 4;
      float4 vs;
      vs.x = acc[i][ob][0] + bias;
      vs.y = acc[i][ob][1] + bias;
      vs.z = acc[i][ob][2] + bias;
      vs.w = acc[i][ob][3] + bias;
      *(float4*)(out + (size_t)p * CD * NN + (size_t)o * NN + nrow) = vs;
    }
}

extern "C" void kernel_launch(void* const* d_in, const int* in_sizes, int n_in,
                              void* d_out, int out_size, void* d_ws, size_t ws_size,
                              hipStream_t stream) {
  const float* x = (const float*)d_in[0];
  const float* wqkv = (const float*)d_in[1];
  const float* wproj = (const float*)d_in[2];
  const float* bproj = (const float*)d_in[3];
  float* out = (float*)d_out;
  unsigned short* ws = (unsigned short*)d_ws;
  const size_t SZ = (size_t)NP * NN * CD; // 1,769,472 elements per buffer
  unsigned short* xt = ws;                 // reused as partial O (half 0) after k_qkv
  unsigned short* Qt = ws + SZ;
  unsigned short* Kt = ws + 2 * SZ;
  unsigned short* Vv = ws + 3 * SZ;
  unsigned short* op1 = ws + 4 * SZ;       // [ph][n][32] bf16 partial, half 1
  unsigned short* wq_b = ws + 5 * SZ;
  unsigned short* wp_b = ws + 5 * SZ + 196608;
  float* Lp = (float*)(ws + 5 * SZ + 262144);  // 2*32*NN floats
  unsigned short* op0 = xt;                    // [ph][n][32] bf16 partial, half 0
  hipLaunchKernelGGL(k_prep, dim3(1120), dim3(256), 0, stream, x, xt, wqkv, wproj, wq_b, wp_b);
  hipLaunchKernelGGL(k_qkv, dim3(27, 12, NP), dim3(256), 0, stream, xt, wq_b, Qt, Kt, Vv);
  hipLaunchKernelGGL(k_attn, dim3(27, 32, 2), dim3(256), 0, stream, Qt, Kt, Vv, op0, op1, Lp);
  hipLaunchKernelGGL(k_proj, dim3(27, 8, NP), dim3(128), 0, stream, op0, op1, Lp, wp_b, bproj, out);
}

// Round 12
// 77.588 us; speedup vs baseline: 1.0428x; 1.0428x over previous
//
#include <hip/hip_runtime.h>

#define NP 4
#define NH 8
#define HD 32
#define CD 256
#define NN 1728
#define NT_TILES 27
#define TILE_E 2048   // elements per (ph,tile): 64n x 32c
// SCALE * log2(e): Q pre-scaled so QK^T scores are exp2-ready
#define SCALE_Q2 (0.17677669529663687f * 1.4426950408889634f)

typedef __bf16 bf16x8 __attribute__((ext_vector_type(8)));
typedef __bf16 bf16x4_t __attribute__((ext_vector_type(4)));
typedef short short4_t __attribute__((ext_vector_type(4)));
typedef float f32x4 __attribute__((ext_vector_type(4)));
typedef unsigned short ushort4_t __attribute__((ext_vector_type(4)));
typedef unsigned short ushort8_t __attribute__((ext_vector_type(8)));

__device__ __forceinline__ float bf2f(unsigned short u) {
  unsigned int v = ((unsigned int)u) << 16;
  return __builtin_bit_cast(float, v);
}
__device__ __forceinline__ unsigned short f2bf(float f) {
  unsigned int v = __builtin_bit_cast(unsigned int, f);
  unsigned int r = (v + 0x7FFFu + ((v >> 16) & 1u)) >> 16;
  return (unsigned short)r;
}

// K0: blocks [0,864): x fp32 [p][C][N] -> xt bf16 [p][N][C] (LDS tile transpose)
//     blocks [864,1120): convert weights fp32 -> bf16
__global__ void k_prep(const float* __restrict__ x, unsigned short* __restrict__ xt,
                       const float* __restrict__ wqkv, const float* __restrict__ wproj,
                       unsigned short* __restrict__ wq_b, unsigned short* __restrict__ wp_b) {
  __shared__ __attribute__((aligned(16))) unsigned short tile[64 * 40]; // 80B rows
  int bid = blockIdx.x;
  int t = threadIdx.x;
  if (bid >= 864) {
    int idx = ((bid - 864) * 256 + t) * 4;
    const float* src;
    unsigned short* dst;
    if (idx < 196608) { src = wqkv + idx; dst = wq_b + idx; }
    else { src = wproj + (idx - 196608); dst = wp_b + (idx - 196608); }
    float4 v = *(const float4*)src;
    ushort4_t o;
    o[0] = f2bf(v.x); o[1] = f2bf(v.y); o[2] = f2bf(v.z); o[3] = f2bf(v.w);
    *(ushort4_t*)dst = o;
    return;
  }
  int nb = (bid % 27) * 64, cb = ((bid / 27) & 7) * 32, p = bid / 216;
  {
    int c = t >> 3, ch = t & 7;
    const float* src = x + ((size_t)p * CD + cb + c) * NN + nb + ch * 8;
    float4 v0 = *(const float4*)src;
    float4 v1 = *(const float4*)(src + 4);
    int base = ch * 8;
    tile[(base + 0) * 40 + c] = f2bf(v0.x);
    tile[(base + 1) * 40 + c] = f2bf(v0.y);
    tile[(base + 2) * 40 + c] = f2bf(v0.z);
    tile[(base + 3) * 40 + c] = f2bf(v0.w);
    tile[(base + 4) * 40 + c] = f2bf(v1.x);
    tile[(base + 5) * 40 + c] = f2bf(v1.y);
    tile[(base + 6) * 40 + c] = f2bf(v1.z);
    tile[(base + 7) * 40 + c] = f2bf(v1.w);
  }
  __syncthreads();
  {
    int n = t >> 2, ch = t & 3;
    *(ushort8_t*)(xt + ((size_t)p * NN + nb + n) * CD + cb + ch * 8) =
        *(const ushort8_t*)&tile[n * 40 + ch * 8];
  }
}

// K1: qkv = xt * wqkv^T. Each block is entirely Q (ot 0-3), K (4-7) or V (8-11).
// Q/K epilogue: LDS-bounce [64][72] -> 2 vectorized ushort8 stores per thread.
// Layouts: Qt [ph][n][32] (scaled); Kt [ph][tile][nf4][chunk64][8];
//          Vv [ph][tile][nfcb8][chunk64][4].
__global__ __launch_bounds__(256) void k_qkv(const unsigned short* __restrict__ xt,
                                             const unsigned short* __restrict__ wqkv,
                                             unsigned short* __restrict__ Qt,
                                             unsigned short* __restrict__ Kt,
                                             unsigned short* __restrict__ Vv) {
  __shared__ __attribute__((aligned(16))) unsigned short smem[64 * 72]; // 9216B
  int p = blockIdx.z, ot = blockIdx.y, nt = blockIdx.x;
  int tid = threadIdx.x, w = tid >> 6, lane = tid & 63, l15 = lane & 15, g = lane >> 4;
  int nbase = nt * 64 + w * 16;
  f32x4 acc[4] = {};
  const unsigned short* arow = xt + ((size_t)p * NN + nbase + l15) * CD + g * 8;
  const unsigned short* wrow = wqkv + ((size_t)(ot * 64 + l15)) * CD + g * 8;
  for (int ks = 0; ks < 8; ks++) {
    bf16x8 a = *(const bf16x8*)(arow + ks * 32);
#pragma unroll
    for (int ob = 0; ob < 4; ob++) {
      bf16x8 b = *(const bf16x8*)(wrow + ob * 16 * CD + ks * 32);
      acc[ob] = __builtin_amdgcn_mfma_f32_16x16x32_bf16(a, b, acc[ob], 0, 0, 0);
    }
  }
  int wq = ot >> 2;
  if (wq == 2) {
    // V: direct ushort4 stores (k-contiguous in tiled layout)
#pragma unroll
    for (int ob = 0; ob < 4; ob++) {
      int o = ot * 64 + ob * 16 + l15;
      int rem = o & 255, h = rem >> 5, cc = rem & 31;
      size_t tb = (size_t)(p * NH + h) * (NT_TILES * TILE_E) + nt * TILE_E;
      ushort4_t vs;
      for (int r = 0; r < 4; r++) vs[r] = f2bf(acc[ob][r]);
      *(ushort4_t*)(Vv + tb + (w * 2 + (cc >> 4)) * 256 + (g * 16 + (cc & 15)) * 4) = vs;
    }
    return;
  }
  // Q/K: bounce through LDS, then vectorized stores
  float sc = (wq == 0) ? SCALE_Q2 : 1.0f;
#pragma unroll
  for (int ob = 0; ob < 4; ob++)
    for (int r = 0; r < 4; r++)
      smem[(w * 16 + g * 4 + r) * 72 + ob * 16 + l15] = f2bf(acc[ob][r] * sc);
  __syncthreads();
#pragma unroll
  for (int i = 0; i < 2; i++) {
    int cid = i * 256 + tid;
    int row = cid >> 3, oc8 = cid & 7;
    ushort8_t vv = *(const ushort8_t*)&smem[row * 72 + oc8 * 8];
    int n = nt * 64 + row;
    if (wq == 0) {
      int h = ot * 2 + (oc8 >> 2), cc8 = (oc8 & 3) * 8;
      *(ushort8_t*)(Qt + ((size_t)(p * NH + h) * NN + n) * HD + cc8) = vv;
    } else {
      int h = (ot - 4) * 2 + (oc8 >> 2), cc8 = (oc8 & 3) * 8;
      size_t tb = (size_t)(p * NH + h) * (NT_TILES * TILE_E) + nt * TILE_E;
      *(ushort8_t*)(Kt + tb + (row >> 4) * 512 + ((cc8 >> 3) * 16 + (row & 15)) * 8) = vv;
    }
  }
}

// K2: flash attention, swapped-operand, shift-0 exact softmax, split-KV x2,
// KVBLK=128 (2 tiles staged per barrier). T5: setprio(1) around MFMA clusters
// (independent blocks at different phases -> scheduler has roles to arbitrate).
__global__ __launch_bounds__(256) void k_attn(const unsigned short* __restrict__ Qt,
                                              const unsigned short* __restrict__ Kt,
                                              const unsigned short* __restrict__ Vv,
                                              unsigned short* __restrict__ op0,
                                              unsigned short* __restrict__ op1,
                                              float* __restrict__ Lp) {
  __shared__ __attribute__((aligned(16))) unsigned char lds[2 * 16384];
  int tid = threadIdx.x, w = tid >> 6, lane = tid & 63, l15 = lane & 15, g = lane >> 4;
  int mt = blockIdx.x, ph = blockIdx.y, z = blockIdx.z;
  int tA = z * 14;
  int nPair = z ? 6 : 7;
  bool tail = (z == 1);
  bf16x8 qfrag = *(const bf16x8*)(Qt + ((size_t)ph * NN + mt * 64 + w * 16 + l15) * HD + g * 8);
  const unsigned short* ktb = Kt + (size_t)ph * (NT_TILES * TILE_E);
  const unsigned short* vbg = Vv + (size_t)ph * (NT_TILES * TILE_E);
  f32x4 lsum = {0.f, 0.f, 0.f, 0.f};
  f32x4 oacc[2] = {};  // O^T: col=m=l15, rows c = cb*16 + g*4 + rr
  f32x4 zacc = {0.f, 0.f, 0.f, 0.f};
  const int so = tid * 16;  // staging byte offset (16B per thread per 4KB region)
  // prologue: stage pair 0 (tiles tA, tA+1) into buffer 0
  *(ushort8_t*)(lds + so)         = *(const ushort8_t*)(ktb + tA * TILE_E + tid * 8);
  *(ushort8_t*)(lds + 4096 + so)  = *(const ushort8_t*)(ktb + (tA + 1) * TILE_E + tid * 8);
  *(ushort8_t*)(lds + 8192 + so)  = *(const ushort8_t*)(vbg + tA * TILE_E + tid * 8);
  *(ushort8_t*)(lds + 12288 + so) = *(const ushort8_t*)(vbg + (tA + 1) * TILE_E + tid * 8);
  __syncthreads();
  auto compute = [&](const unsigned char* kb, const unsigned char* vb) {
    f32x4 s[4];
    __builtin_amdgcn_s_setprio(1);
#pragma unroll
    for (int nf = 0; nf < 4; nf++) {
      bf16x8 kbv = *(const bf16x8*)(kb + nf * 1024 + lane * 16);
      s[nf] = __builtin_amdgcn_mfma_f32_16x16x32_bf16(kbv, qfrag, zacc, 0, 0, 0);
    }
    __builtin_amdgcn_s_setprio(0);
    short4_t pa[4];
#pragma unroll
    for (int nf = 0; nf < 4; nf++) {
      f32x4 e;
#pragma unroll
      for (int r = 0; r < 4; r++) e[r] = __builtin_amdgcn_exp2f(s[nf][r]);
      lsum += e;
      bf16x4_t t;
#pragma unroll
      for (int r = 0; r < 4; r++) t[r] = (__bf16)e[r];
      pa[nf] = __builtin_bit_cast(short4_t, t);
    }
    __builtin_amdgcn_s_setprio(1);
#pragma unroll
    for (int nf = 0; nf < 4; nf++) {
#pragma unroll
      for (int cb = 0; cb < 2; cb++) {
        ushort4_t vq = *(const ushort4_t*)(vb + (nf * 2 + cb) * 512 + lane * 8);
        short4_t va = __builtin_bit_cast(short4_t, vq);
        oacc[cb] = __builtin_amdgcn_mfma_f32_16x16x16bf16_1k(va, pa[nf], oacc[cb], 0, 0, 0);
      }
    }
    __builtin_amdgcn_s_setprio(0);
  };
  for (int pr = 0; pr < nPair; pr++) {
    unsigned char* buf = lds + (pr & 1) * 16384;
    unsigned char* bufN = lds + ((pr + 1) & 1) * 16384;
    ushort8_t kr0, kr1, vr0, vr1;
    bool pre = (pr + 1 < nPair);
    bool preT = tail && (pr + 1 == nPair);
    if (pre) {
      int d = tA + 2 * (pr + 1);
      kr0 = *(const ushort8_t*)(ktb + d * TILE_E + tid * 8);
      kr1 = *(const ushort8_t*)(ktb + (d + 1) * TILE_E + tid * 8);
      vr0 = *(const ushort8_t*)(vbg + d * TILE_E + tid * 8);
      vr1 = *(const ushort8_t*)(vbg + (d + 1) * TILE_E + tid * 8);
    } else if (preT) {
      kr0 = *(const ushort8_t*)(ktb + 26 * TILE_E + tid * 8);
      vr0 = *(const ushort8_t*)(vbg + 26 * TILE_E + tid * 8);
    }
    compute(buf, buf + 8192);
    compute(buf + 4096, buf + 12288);
    if (pre) {
      *(ushort8_t*)(bufN + so) = kr0;
      *(ushort8_t*)(bufN + 4096 + so) = kr1;
      *(ushort8_t*)(bufN + 8192 + so) = vr0;
      *(ushort8_t*)(bufN + 12288 + so) = vr1;
    } else if (preT) {
      *(ushort8_t*)(bufN + so) = kr0;
      *(ushort8_t*)(bufN + 8192 + so) = vr0;
    }
    __syncthreads();
  }
  if (tail) {
    unsigned char* buf = lds + (nPair & 1) * 16384;
    compute(buf, buf + 8192);
  }
  // deferred cross-lane sum reduce; store raw partials (no normalization yet)
  float total = lsum[0] + lsum[1] + lsum[2] + lsum[3];
  total += __shfl_xor(total, 16);
  total += __shfl_xor(total, 32);
  int m = mt * 64 + w * 16 + l15;
  unsigned short* op = z ? op1 : op0;
  if (g == 0) Lp[(size_t)z * 32 * NN + (size_t)ph * NN + m] = total;
#pragma unroll
  for (int cb = 0; cb < 2; cb++) {
    ushort4_t vs;
#pragma unroll
    for (int rr = 0; rr < 4; rr++) vs[rr] = f2bf(oacc[cb][rr]);
    *(ushort4_t*)(op + ((size_t)ph * NN + m) * 32 + cb * 16 + g * 4) = vs;
  }
}

// K3: fused combine+proj: out[p][o][n] = wproj · [(O0+O1)/(L0+L1)] + bias  (fp32 out)
__global__ __launch_bounds__(256) void k_proj(const unsigned short* __restrict__ op0,
                                              const unsigned short* __restrict__ op1,
                                              const float* __restrict__ Lp,
                                              const unsigned short* __restrict__ wproj,
                                              const float* __restrict__ bproj,
                                              float* __restrict__ out) {
  int p = blockIdx.z, ot = blockIdx.y, nt = blockIdx.x;
  int tid = threadIdx.x, w = tid >> 6, lane = tid & 63, l15 = lane & 15, g = lane >> 4;
  int nbase = nt * 64 + w * 16;
  int n = nbase + l15;
  f32x4 acc[4] = {};
  const unsigned short* wrow = wproj + ((size_t)(ot * 64 + l15)) * CD + g * 8;
  for (int ks = 0; ks < 8; ks++) {
    size_t r = (size_t)(p * NH + ks) * NN + n;
    float inv = 1.0f / (Lp[r] + Lp[(size_t)32 * NN + r]);
    ushort8_t a0 = *(const ushort8_t*)(op0 + r * 32 + g * 8);
    ushort8_t a1 = *(const ushort8_t*)(op1 + r * 32 + g * 8);
    bf16x8 a;
#pragma unroll
    for (int j = 0; j < 8; j++) a[j] = (__bf16)((bf2f(a0[j]) + bf2f(a1[j])) * inv);
#pragma unroll
    for (int ob = 0; ob < 4; ob++) {
      bf16x8 b = *(const bf16x8*)(wrow + ob * 16 * CD + ks * 32);
      acc[ob] = __builtin_amdgcn_mfma_f32_16x16x32_bf16(a, b, acc[ob], 0, 0, 0);
    }
  }
#pragma unroll
  for (int ob = 0; ob < 4; ob++) {
    int o = ot * 64 + ob * 16 + l15;
    float bias = bproj[o];
    int nrow = nbase + g * 4;
    float4 vs;
    vs.x = acc[ob][0] + bias;
    vs.y = acc[ob][1] + bias;
    vs.z = acc[ob][2] + bias;
    vs.w = acc[ob][3] + bias;
    *(float4*)(out + (size_t)p * CD * NN + (size_t)o * NN + nrow) = vs;
  }
}

extern "C" void kernel_launch(void* const* d_in, const int* in_sizes, int n_in,
                              void* d_out, int out_size, void* d_ws, size_t ws_size,
                              hipStream_t stream) {
  const float* x = (const float*)d_in[0];
  const float* wqkv = (const float*)d_in[1];
  const float* wproj = (const float*)d_in[2];
  const float* bproj = (const float*)d_in[3];
  float* out = (float*)d_out;
  unsigned short* ws = (unsigned short*)d_ws;
  const size_t SZ = (size_t)NP * NN * CD; // 1,769,472 elements per buffer
  unsigned short* xt = ws;                 // reused as partial O (half 0) after k_qkv
  unsigned short* Qt = ws + SZ;
  unsigned short* Kt = ws + 2 * SZ;
  unsigned short* Vv = ws + 3 * SZ;
  unsigned short* op1 = ws + 4 * SZ;       // [ph][n][32] bf16 partial, half 1
  unsigned short* wq_b = ws + 5 * SZ;
  unsigned short* wp_b = ws + 5 * SZ + 196608;
  float* Lp = (float*)(ws + 5 * SZ + 262144);  // 2*32*NN floats
  unsigned short* op0 = xt;                    // [ph][n][32] bf16 partial, half 0
  hipLaunchKernelGGL(k_prep, dim3(1120), dim3(256), 0, stream, x, xt, wqkv, wproj, wq_b, wp_b);
  hipLaunchKernelGGL(k_qkv, dim3(27, 12, NP), dim3(256), 0, stream, xt, wq_b, Qt, Kt, Vv);
  hipLaunchKernelGGL(k_attn, dim3(27, 32, 2), dim3(256), 0, stream, Qt, Kt, Vv, op0, op1, Lp);
  hipLaunchKernelGGL(k_proj, dim3(27, 4, NP), dim3(256), 0, stream, op0, op1, Lp, wp_b, bproj, out);
}